// Round 6
// baseline (245.674 us; speedup 1.0000x reference)
//
#include <hip/hip_runtime.h>

// PDELoss fused. R6: bulk LDS staging + latency-free compute loop.
// Toolchain laws learned R2-R5: (a) __launch_bounds__ 2nd arg CAPS residency
// at n waves/SIMD; (b) arch-VGPR budget ~256/n (half the unified file goes to
// unused AGPRs) -> n>4 spills this kernel. So n=4 is fixed; instead of more
// waves, remove latency: each block stages its whole pred(20-row)+rhs(16-row)
// tile into LDS with 9 independent dwordx4 loads/thread (huge MLP), one
// barrier, then the proven R5 register pipeline reads LDS only (no global,
// no vmcnt in loop). LDS 36.2 KB -> 4 blocks/CU == residency cap. Grid:
// 256 images x 16 strips = 4096 blocks.

__global__ __launch_bounds__(256, 4)
void pde_loss_kernel(const float* __restrict__ pred,   // [B,256,256]
                     const float* __restrict__ rhs,    // [B,254,254]
                     const float* __restrict__ KL,     // [B,3,3]
                     const float* __restrict__ KD,     // [B,3,3]
                     const float* __restrict__ RR,     // [B,256,256] (col-only)
                     const float* __restrict__ ZZ,     // [B,256,256] (row-only)
                     float* __restrict__ out,
                     float inv_n)
{
    constexpr int H = 256, W = 256, OH = 254, OW = 254;
    const int tid = threadIdx.x;
    const int l   = tid & 63;          // lane
    const int wv  = tid >> 6;          // wave in block
    const int b   = blockIdx.x >> 4;   // image (16 strips/image)
    const int o0T = (blockIdx.x & 15) * 16;   // block strip start (output rows)

    __shared__ float predT[20][256];   // pred rows o0T-1 .. o0T+18 (20 KB)
    __shared__ float rhsT[16][256];    // rhs rows o0T .. o0T+15 (16 KB; cols 254,255 garbage)
    __shared__ float wsum[4];

    const size_t ib = (size_t)b * H * W;
    const float* predb = pred + ib;
    const float* rhsb  = rhs + (size_t)b * OH * OW;

    // ---- bulk stage: 9 independent dwordx4-class loads per thread ----
#pragma unroll
    for (int k = 0; k < 5; ++k) {                 // pred: 20 rows x 64 chunks
        const int idx = tid + k * 256;
        const int tr = idx >> 6, cq = idx & 63;
        const int gr = o0T - 1 + tr;
        if (gr >= 0 && gr < H)
            *(float4*)&predT[tr][cq * 4] = *(const float4*)(predb + (size_t)gr * W + cq * 4);
    }
#pragma unroll
    for (int k = 0; k < 4; ++k) {                 // rhs: 16 rows x 64 chunks
        const int idx = tid + k * 256;
        const int tr = idx >> 6, cq = idx & 63;
        const int ro = o0T + tr;
        if (ro < OH) {
            const float* src = rhsb + (size_t)ro * OW + cq * 4;
            if (cq < 63) *(float4*)&rhsT[tr][cq * 4] = *(const float4*)src;
            else         *(float2*)&rhsT[tr][252]    = *(const float2*)src;  // avoid 1-past-end read
        }
    }

    // ---- per-sample folded coefficients (independent global reads) ----
    const float hr  = RR[ib + W + 2] - RR[ib + W + 1];
    const float hz  = ZZ[ib + 2 * W + 1] - ZZ[ib + W + 1];
    const float hr2 = hr * hr, hz2 = hz * hz;
    const float s   = -2.0f * (hr2 + hz2) / (hr2 * hz2);

    const int c0 = 4 * l;
    float4 c4[9];
    {
        float4 invr;
        invr.x = 1.0f / RR[ib + W + (c0 + 1)];
        invr.y = 1.0f / RR[ib + W + (c0 + 2)];
        invr.z = 1.0f / RR[ib + W + (c0 + 3)];
        invr.w = 1.0f / RR[ib + W + ((c0 + 4 < W) ? (c0 + 4) : (W - 1))];
        const float* kl = KL + b * 9;
        const float* kd = KD + b * 9;
#pragma unroll
        for (int t = 0; t < 9; ++t) {
            const float a = kl[t] * s, d = kd[t] * s;
            c4[t].x = fmaf(d, invr.x, a);
            c4[t].y = fmaf(d, invr.y, a);
            c4[t].z = fmaf(d, invr.z, a);
            c4[t].w = fmaf(d, invr.w, a);
        }
    }

    __syncthreads();   // tile ready

    // ---- wave sub-strip: 4 output rows per wave ----
    const int o0 = o0T + 4 * wv;
    const int o1 = (o0 + 4 < OH) ? (o0 + 4) : OH;

    const int g0 = o0 - 1;
    float4 pa = make_float4(0.f, 0.f, 0.f, 0.f), pb, pc;
    if (g0 >= 0) pa = *(const float4*)&predT[g0 - o0T + 1][c0];
    pb = *(const float4*)&predT[g0 - o0T + 2][c0];
    pc = *(const float4*)&predT[g0 - o0T + 3][c0];
    float nxa = __shfl(pa.x, l + 1, 64), nya = __shfl(pa.y, l + 1, 64);
    float nxb = __shfl(pb.x, l + 1, 64), nyb = __shfl(pb.y, l + 1, 64);

    float4 ghA = make_float4(0.f, 0.f, 0.f, 0.f);
    float4 ghB = make_float4(0.f, 0.f, 0.f, 0.f);
    float acc = 0.0f;

    for (int g = g0; g <= o1; ++g) {
        // next pred row from LDS (tile row rowp - o0T + 1)
        float4 pn = make_float4(0.f, 0.f, 0.f, 0.f);
        const int rowp = g + 3;
        if (rowp < H && rowp <= o1 + 2)
            pn = *(const float4*)&predT[rowp - o0T + 1][c0];

        const float nxc = __shfl(pc.x, l + 1, 64);
        const float nyc = __shfl(pc.y, l + 1, 64);

        // GS_ope row g (zero outside [0,OH): SAME padding)
        float4 gs = make_float4(0.f, 0.f, 0.f, 0.f);
        if ((unsigned)g < (unsigned)OH) {
#define ROWC(p, nx, ny, t0)                                              \
            gs.x = fmaf(p.x, c4[t0].x, fmaf(p.y, c4[t0+1].x, fmaf(p.z, c4[t0+2].x, gs.x))); \
            gs.y = fmaf(p.y, c4[t0].y, fmaf(p.z, c4[t0+1].y, fmaf(p.w, c4[t0+2].y, gs.y))); \
            gs.z = fmaf(p.z, c4[t0].z, fmaf(p.w, c4[t0+1].z, fmaf(nx,  c4[t0+2].z, gs.z))); \
            gs.w = fmaf(p.w, c4[t0].w, fmaf(nx,  c4[t0+1].w, fmaf(ny,  c4[t0+2].w, gs.w)));
            ROWC(pa, nxa, nya, 0)
            ROWC(pb, nxb, nyb, 3)
            ROWC(pc, nxc, nyc, 6)
#undef ROWC
            if (l == 63) { gs.z = 0.f; gs.w = 0.f; }   // cols 254,255 out of range
        }

        // horizontal [1,2,1]
        float up = __shfl(gs.w, l - 1, 64);
        const float dn = __shfl(gs.x, l + 1, 64);     // lane 63: garbage, unused
        if (l == 0) up = 0.f;
        float4 gh;
        gh.x = fmaf(2.f, gs.x, up   + gs.y);
        gh.y = fmaf(2.f, gs.y, gs.x + gs.z);
        gh.z = fmaf(2.f, gs.z, gs.y + gs.w);
        gh.w = fmaf(2.f, gs.w, gs.z + dn);

        // vertical [1,2,1]/16, emit row i = g-1, MSE accumulate (rhs from LDS)
        const int i = g - 1;
        if (i >= o0 && i < o1) {
            const float4 r = *(const float4*)&rhsT[i - o0T][c0];
            const float smx = (ghA.x + 2.f * ghB.x + gh.x) * 0.0625f;
            const float smy = (ghA.y + 2.f * ghB.y + gh.y) * 0.0625f;
            const float smz = (ghA.z + 2.f * ghB.z + gh.z) * 0.0625f;
            const float smw = (ghA.w + 2.f * ghB.w + gh.w) * 0.0625f;
            const float dx = smx - r.x;
            const float dy = smy - r.y;
            float dz = smz - r.z;
            float dw = smw - r.w;
            if (c0 + 2 >= OW) { dz = 0.f; dw = 0.f; }   // lane 63 tail cols (garbage r.z/r.w)
            acc = fmaf(dx, dx, acc);
            acc = fmaf(dy, dy, acc);
            acc = fmaf(dz, dz, acc);
            acc = fmaf(dw, dw, acc);
        }

        // roll
        pa = pb; pb = pc; pc = pn;
        nxa = nxb; nya = nyb; nxb = nxc; nyb = nyc;
        ghA = ghB; ghB = gh;
    }

    // wave reduce -> block reduce -> one atomic per block
#pragma unroll
    for (int off = 32; off > 0; off >>= 1)
        acc += __shfl_down(acc, off, 64);
    if (l == 0) wsum[wv] = acc;
    __syncthreads();
    if (tid == 0) {
        const float t = (wsum[0] + wsum[1]) + (wsum[2] + wsum[3]);
        atomicAdd(out, t * inv_n);
    }
}

extern "C" void kernel_launch(void* const* d_in, const int* in_sizes, int n_in,
                              void* d_out, int out_size, void* d_ws, size_t ws_size,
                              hipStream_t stream) {
    const float* pred = (const float*)d_in[0];
    const float* rhs  = (const float*)d_in[1];
    const float* KL   = (const float*)d_in[2];
    const float* KD   = (const float*)d_in[3];
    const float* RR   = (const float*)d_in[4];
    const float* ZZ   = (const float*)d_in[5];
    // d_in[6] = Gauss kernel [[1,2,1],[2,4,2],[1,2,1]]/16 — hardcoded, separable
    float* out = (float*)d_out;

    const int B = in_sizes[2] / 9;   // 256
    const float inv_n = 1.0f / ((float)B * 254.0f * 254.0f);

    hipMemsetAsync(out, 0, sizeof(float), stream);
    pde_loss_kernel<<<dim3(B * 16), dim3(256), 0, stream>>>(pred, rhs, KL, KD, RR, ZZ, out, inv_n);
}

// Round 7
// 226.786 us; speedup vs baseline: 1.0833x; 1.0833x over previous
//
#include <hip/hip_runtime.h>

// PDELoss fused, wave-autonomous. R7 = R5 kernel with the residency cap
// REMOVED. Empirical law (R2-R6, 5/5 rounds): __launch_bounds__'s 2nd arg
// acts as a waves-per-EU *cap* on this toolchain (occupancy 35/58/71-86% at
// caps 4/6/8) while also halving the VGPR budget for phantom AGPRs (spill at
// cap>=6). Plain __launch_bounds__(256) imposes no cap: at 52 VGPR the HW
// allows 512/52 -> 8 waves/SIMD -> 32 waves/CU from the 8192-wave grid.
// Structure unchanged from R5: wave owns (image, 8-row strip), thread = 4
// cols (float4), per-lane folded coefs c4[9], shfl halos, rolling 3-row
// register window, 1-iteration prefetch distance on pred & rhs.

__global__ __launch_bounds__(256)
void pde_loss_kernel(const float* __restrict__ pred,   // [B,256,256]
                     const float* __restrict__ rhs,    // [B,254,254]
                     const float* __restrict__ KL,     // [B,3,3]
                     const float* __restrict__ KD,     // [B,3,3]
                     const float* __restrict__ RR,     // [B,256,256] (col-only)
                     const float* __restrict__ ZZ,     // [B,256,256] (row-only)
                     float* __restrict__ out,
                     float inv_n)
{
    constexpr int H = 256, W = 256, OH = 254, OW = 254;
    const int tid = threadIdx.x;
    const int l   = tid & 63;          // lane
    const int wv  = tid >> 6;          // wave in block
    const int b   = blockIdx.x >> 3;   // image (8 blocks/image)
    const int strip = (blockIdx.x & 7) * 4 + wv;   // 32 strips of 8 rows
    const int o0 = strip * 8;
    const int o1 = (o0 + 8 < OH) ? (o0 + 8) : OH;  // last strip: 6 rows

    const size_t ib = (size_t)b * H * W;
    const float* predb = pred + ib;
    const float* rhsb  = rhs + (size_t)b * OH * OW;

    const float hr  = RR[ib + W + 2] - RR[ib + W + 1];
    const float hz  = ZZ[ib + 2 * W + 1] - ZZ[ib + W + 1];
    const float hr2 = hr * hr, hz2 = hz * hz;
    const float s   = -2.0f * (hr2 + hz2) / (hr2 * hz2);

    // Per-column folded coefficients: c4[t] over the 4 owned cols c0..c0+3
    const int c0 = 4 * l;
    float4 c4[9];
    {
        float4 invr;
        invr.x = 1.0f / RR[ib + W + (c0 + 1)];
        invr.y = 1.0f / RR[ib + W + (c0 + 2)];
        invr.z = 1.0f / RR[ib + W + (c0 + 3)];
        invr.w = 1.0f / RR[ib + W + ((c0 + 4 < W) ? (c0 + 4) : (W - 1))];
        const float* kl = KL + b * 9;
        const float* kd = KD + b * 9;
#pragma unroll
        for (int t = 0; t < 9; ++t) {
            const float a = kl[t] * s, d = kd[t] * s;
            c4[t].x = fmaf(d, invr.x, a);
            c4[t].y = fmaf(d, invr.y, a);
            c4[t].z = fmaf(d, invr.z, a);
            c4[t].w = fmaf(d, invr.w, a);
        }
    }

    // Prologue: rolling pred rows g0..g0+2 (pa,pb,pc) + shfl halos
    const int g0 = o0 - 1;
    float4 pa = make_float4(0.f, 0.f, 0.f, 0.f), pb, pc;
    if (g0 >= 0) pa = *(const float4*)(predb + (size_t)g0 * W + c0);
    pb = *(const float4*)(predb + (size_t)(g0 + 1) * W + c0);
    pc = *(const float4*)(predb + (size_t)(g0 + 2) * W + c0);
    float nxa = __shfl(pa.x, l + 1, 64), nya = __shfl(pa.y, l + 1, 64);
    float nxb = __shfl(pb.x, l + 1, 64), nyb = __shfl(pb.y, l + 1, 64);

    float4 ghA = make_float4(0.f, 0.f, 0.f, 0.f);
    float4 ghB = make_float4(0.f, 0.f, 0.f, 0.f);
    float2 rc0 = make_float2(0.f, 0.f), rc1 = make_float2(0.f, 0.f);
    float acc = 0.0f;

    for (int g = g0; g <= o1; ++g) {
        // --- prefetch pred row g+3 (consumed next iteration as pc) ---
        float4 pn = make_float4(0.f, 0.f, 0.f, 0.f);
        const int rowp = g + 3;
        if (rowp < H && rowp <= o1 + 2)
            pn = *(const float4*)(predb + (size_t)rowp * W + c0);

        // --- prefetch rhs row g (consumed next iteration at emit i=g) ---
        float2 rn0 = make_float2(0.f, 0.f), rn1 = make_float2(0.f, 0.f);
        if (g >= o0 && g < o1) {
            const float* rrow = rhsb + (size_t)g * OW + c0;
            rn0 = *(const float2*)rrow;
            if (c0 + 2 < OW) rn1 = *(const float2*)(rrow + 2);
        }

        // --- halos for the row newly in position c (loaded last iter) ---
        const float nxc = __shfl(pc.x, l + 1, 64);
        const float nyc = __shfl(pc.y, l + 1, 64);

        // --- GS_ope row g (zero outside [0,OH): SAME padding) ---
        float4 gs = make_float4(0.f, 0.f, 0.f, 0.f);
        if ((unsigned)g < (unsigned)OH) {
#define ROWC(p, nx, ny, t0)                                              \
            gs.x = fmaf(p.x, c4[t0].x, fmaf(p.y, c4[t0+1].x, fmaf(p.z, c4[t0+2].x, gs.x))); \
            gs.y = fmaf(p.y, c4[t0].y, fmaf(p.z, c4[t0+1].y, fmaf(p.w, c4[t0+2].y, gs.y))); \
            gs.z = fmaf(p.z, c4[t0].z, fmaf(p.w, c4[t0+1].z, fmaf(nx,  c4[t0+2].z, gs.z))); \
            gs.w = fmaf(p.w, c4[t0].w, fmaf(nx,  c4[t0+1].w, fmaf(ny,  c4[t0+2].w, gs.w)));
            ROWC(pa, nxa, nya, 0)
            ROWC(pb, nxb, nyb, 3)
            ROWC(pc, nxc, nyc, 6)
#undef ROWC
            if (l == 63) { gs.z = 0.f; gs.w = 0.f; }   // cols 254,255 out of range
        }

        // --- horizontal [1,2,1] ---
        float up = __shfl(gs.w, l - 1, 64);
        const float dn = __shfl(gs.x, l + 1, 64);     // lane 63: garbage, unused
        if (l == 0) up = 0.f;
        float4 gh;
        gh.x = fmaf(2.f, gs.x, up   + gs.y);
        gh.y = fmaf(2.f, gs.y, gs.x + gs.z);
        gh.z = fmaf(2.f, gs.z, gs.y + gs.w);
        gh.w = fmaf(2.f, gs.w, gs.z + dn);

        // --- vertical [1,2,1]/16, emit row i = g-1, MSE accumulate ---
        const int i = g - 1;
        if (i >= o0 && i < o1) {
            const float smx = (ghA.x + 2.f * ghB.x + gh.x) * 0.0625f;
            const float smy = (ghA.y + 2.f * ghB.y + gh.y) * 0.0625f;
            const float smz = (ghA.z + 2.f * ghB.z + gh.z) * 0.0625f;
            const float smw = (ghA.w + 2.f * ghB.w + gh.w) * 0.0625f;
            const float dx = smx - rc0.x;
            const float dy = smy - rc0.y;
            float dz = smz - rc1.x;
            float dw = smw - rc1.y;
            if (c0 + 2 >= OW) { dz = 0.f; dw = 0.f; }   // lane 63 tail cols
            acc = fmaf(dx, dx, acc);
            acc = fmaf(dy, dy, acc);
            acc = fmaf(dz, dz, acc);
            acc = fmaf(dw, dw, acc);
        }

        // --- roll ---
        pa = pb; pb = pc; pc = pn;
        nxa = nxb; nya = nyb; nxb = nxc; nyb = nyc;
        ghA = ghB; ghB = gh;
        rc0 = rn0; rc1 = rn1;
    }

    // wave reduce -> block reduce -> one atomic per block
#pragma unroll
    for (int off = 32; off > 0; off >>= 1)
        acc += __shfl_down(acc, off, 64);
    __shared__ float wsum[4];
    if (l == 0) wsum[wv] = acc;
    __syncthreads();
    if (tid == 0) {
        const float t = (wsum[0] + wsum[1]) + (wsum[2] + wsum[3]);
        atomicAdd(out, t * inv_n);
    }
}

extern "C" void kernel_launch(void* const* d_in, const int* in_sizes, int n_in,
                              void* d_out, int out_size, void* d_ws, size_t ws_size,
                              hipStream_t stream) {
    const float* pred = (const float*)d_in[0];
    const float* rhs  = (const float*)d_in[1];
    const float* KL   = (const float*)d_in[2];
    const float* KD   = (const float*)d_in[3];
    const float* RR   = (const float*)d_in[4];
    const float* ZZ   = (const float*)d_in[5];
    // d_in[6] = Gauss kernel [[1,2,1],[2,4,2],[1,2,1]]/16 — hardcoded, separable
    float* out = (float*)d_out;

    const int B = in_sizes[2] / 9;   // 256
    const float inv_n = 1.0f / ((float)B * 254.0f * 254.0f);

    hipMemsetAsync(out, 0, sizeof(float), stream);
    pde_loss_kernel<<<dim3(B * 8), dim3(256), 0, stream>>>(pred, rhs, KL, KD, RR, ZZ, out, inv_n);
}